// Round 4
// baseline (306.818 us; speedup 1.0000x reference)
//
#include <hip/hip_runtime.h>
#include <math.h>

#define BB 32
#define NCLS 15
#define HH 256
#define WW 256
#define KK 500
#define HW (HH*WW)                 // 65536
#define NELEM (BB*NCLS*HW)         // 31457280
#define N4 (NELEM/4)               // 7864320 float4s
#define NM (BB*NCLS*16*16)         // 122880 multiplier slots
#define BK (BB*KK)                 // 16000

// k_main flat sweep: 2048 blocks x 256 thr, grid stride 524288 float4s.
// N4 / MGS = 15 exactly -> no bounds check, whole grid advances as ONE
// contiguous 8MB front per array (row-buffer/TLB-friendly), vs R3's
// 480 independent plane-sweeps (960 streams) that sat at 1.2 TB/s HBM.
#define MG 2048
#define MT 256
#define MGS (MG*MT)
#define MITER (N4/MGS)             // 15

// ws layout (floats):
//  f[0] = S  f[1] = num_pos  i[2] = last (init -1)  i[3] = corr block counter
//  f[4 .. 4+BK) = l_bk   f[16384 .. 16384+NM) = multiplier table M (init 1.0)
#define OFF_LBK 4
#define OFF_M   16384

__constant__ float c_gammas[15] = {2.7f,2.1f,2.4f,2.0f,3.0f,2.9f,3.0f,2.5f,
                                   2.1f,2.6f,2.0f,2.1f,2.7f,2.4f,2.2f};

// Raw HW transcendentals (glibc collides with __exp2f/__log2f names):
#define EXP2F(x) __builtin_amdgcn_exp2f(x)
#define LOG2F(x) __builtin_amdgcn_logf(x)
#define LN2 0.69314718055994530942f

__device__ __forceinline__ float elem(float p, float g, float gam, float& np) {
    float t    = 1.0f - g;
    float t2   = t * t;
    float negw = (g < 1.0f) ? t2 * t2 : 0.0f;          // (1-g)^4 * neg_ind
    float pw   = EXP2F(gam * LOG2F(p));                // p^gam (0 -> 0)
    float v    = (LN2 * LOG2F(1.0f - p + 1e-12f)) * pw * negw;
    if (g == 1.0f) {                                   // ~never taken
        np += 1.0f;
        v += (LN2 * LOG2F(p + 1e-12f)) * EXP2F(gam * LOG2F(1.0f - p));
    }
    return v;
}

__device__ __forceinline__ float blockReduceSum(float v) {
    __shared__ float sh[4];
    #pragma unroll
    for (int o = 32; o > 0; o >>= 1) v += __shfl_down(v, o);
    int lane = threadIdx.x & 63, w = threadIdx.x >> 6;
    if (lane == 0) sh[w] = v;
    __syncthreads();
    float r = 0.0f;
    if (threadIdx.x == 0) r = sh[0] + sh[1] + sh[2] + sh[3];
    __syncthreads();
    return r;   // valid on thread 0 only
}

// ---- init: zero scalars, last=-1, corr counter=0, M=1.0 ----
__global__ __launch_bounds__(256) void k_init(float* ws) {
    int i = blockIdx.x * blockDim.x + threadIdx.x;
    if (i == 0) {
        ws[0] = 0.0f;
        ws[1] = 0.0f;
        ((int*)ws)[2] = -1;
        ((int*)ws)[3] = 0;
    }
    if (i < NM) ws[OFF_M + i] = 1.0f;
}

// ---- per-(b,k): huber mean, l_bk, last, scatter-multiply into M ----
__global__ __launch_bounds__(256) void k_bk(const float* __restrict__ output,
                                            const int*   __restrict__ mask,
                                            const int*   __restrict__ ind,
                                            const float* __restrict__ target,
                                            const int*   __restrict__ inde,
                                            float* ws) {
    int t = blockIdx.x * blockDim.x + threadIdx.x;
    int lastv = -1;
    if (t < BK) {
        int b = t / KK;
        int pos = ind[t];                                    // 0..HW-1
        const float* ob = output + (size_t)b * 2 * HW;
        float p0 = ob[pos];
        float p1 = ob[HW + pos];
        float d0 = p0 - target[t*2 + 0];
        float d1 = p1 - target[t*2 + 1];
        float a0 = fabsf(d0), a1 = fabsf(d1);
        float h0 = (a0 < 1.0f) ? 0.5f*d0*d0 : a0 - 0.5f;
        float h1 = (a1 < 1.0f) ? 0.5f*d1*d1 : a1 - 0.5f;
        float l  = 0.5f * (h0 + h1);
        ws[OFF_LBK + t] = l;
        if (mask[t] != 0) {
            lastv = t;
            float factor = atanf(l) * 0.63661977236758134308f;  // 2/pi
            int ch = inde[t*3 + 0];
            int yy = inde[t*3 + 1];
            int xx = inde[t*3 + 2];
            int mi = ((b*NCLS + ch)*16 + yy)*16 + xx;
            unsigned int* addr = (unsigned int*)(ws + OFF_M + mi);
            unsigned int old = *addr, assumed;
            do {
                assumed = old;
                float nv = __uint_as_float(assumed) * factor;
                old = atomicCAS(addr, assumed, __float_as_uint(nv));
            } while (old != assumed);
        }
    }
    // block-level max of lastv -> one atomicMax per block
    __shared__ int shm[4];
    int v = lastv;
    #pragma unroll
    for (int o = 32; o > 0; o >>= 1) v = max(v, __shfl_down(v, o));
    int lane = threadIdx.x & 63, w = threadIdx.x >> 6;
    if (lane == 0) shm[w] = v;
    __syncthreads();
    if (threadIdx.x == 0) {
        int m = max(max(shm[0], shm[1]), max(shm[2], shm[3]));
        if (m >= 0) atomicMax(((int*)ws) + 2, m);
    }
}

// ---- main reduction: flat contiguous grid-wide sweep ----
__global__ __launch_bounds__(256) void k_main(const float4* __restrict__ pred,
                                              const float4* __restrict__ gt,
                                              float* ws) {
    int t = blockIdx.x * MT + threadIdx.x;
    float acc = 0.0f, np = 0.0f;
    #pragma unroll 5
    for (int k = 0; k < MITER; ++k) {
        int i = t + k * MGS;
        float4 p = pred[i];
        float4 g = gt[i];
        int c = (i >> 14) % NCLS;          // plane = i / (HW/4), channel = plane % 15
        float gam = c_gammas[c];
        acc += gam * (elem(p.x, g.x, gam, np) + elem(p.y, g.y, gam, np)
                    + elem(p.z, g.z, gam, np) + elem(p.w, g.w, gam, np));
    }
    float bs = blockReduceSum(acc);
    if (threadIdx.x == 0 && bs != 0.0f) atomicAdd(&ws[0], bs);
    float bn = blockReduceSum(np);
    if (threadIdx.x == 0 && bn != 0.0f) atomicAdd(&ws[1], bn);
}

// ---- correction at scatter-modified locations + fused finalize ----
// grid must be exactly NM/256 = 480 blocks (counter pattern assumes it).
__global__ __launch_bounds__(256) void k_corr(const float* __restrict__ pred,
                                              const float* __restrict__ gt,
                                              float* ws, float* out) {
    int i = blockIdx.x * blockDim.x + threadIdx.x;
    float acc = 0.0f, dummy = 0.0f;
    float m = ws[OFF_M + i];
    if (m != 1.0f) {
        int x  = i & 15;
        int y  = (i >> 4) & 15;
        int bc = i >> 8;
        int c  = bc % NCLS;
        size_t off = ((size_t)bc << 16) + (size_t)(y * WW + x);
        float p = pred[off];
        float g = gt[off];
        float gam = c_gammas[c];
        acc = gam * (elem(p * m, g, gam, dummy) - elem(p, g, gam, dummy));
    }
    float bs = blockReduceSum(acc);
    if (threadIdx.x == 0) {
        if (bs != 0.0f) atomicAdd(&ws[0], bs);
        __threadfence();                                   // flush my add
        int done = atomicAdd(((int*)ws) + 3, 1);
        if (done == gridDim.x - 1) {                       // last block finalizes
            float S  = atomicAdd(&ws[0], 0.0f);            // coherent reads
            float np = atomicAdd(&ws[1], 0.0f);
            int last = ((volatile int*)ws)[2];             // written by k_bk (prior kernel)
            float loss0 = (last >= 0) ? ws[OFF_LBK + last] : 0.0f;
            float loss = loss0 - 0.5f * S;
            out[0] = (np == 0.0f) ? loss : loss / np;
        }
    }
}

extern "C" void kernel_launch(void* const* d_in, const int* in_sizes, int n_in,
                              void* d_out, int out_size, void* d_ws, size_t ws_size,
                              hipStream_t stream) {
    const float* pred   = (const float*)d_in[0];
    const float* gt     = (const float*)d_in[1];
    const float* output = (const float*)d_in[2];
    const int*   mask   = (const int*)d_in[3];
    const int*   ind    = (const int*)d_in[4];
    const float* target = (const float*)d_in[5];
    const int*   inde   = (const int*)d_in[6];
    float* ws  = (float*)d_ws;
    float* out = (float*)d_out;

    k_init<<<(NM + 255)/256, 256, 0, stream>>>(ws);
    k_bk  <<<(BK + 255)/256, 256, 0, stream>>>(output, mask, ind, target, inde, ws);
    k_main<<<MG, MT, 0, stream>>>((const float4*)pred, (const float4*)gt, ws);
    k_corr<<<NM/256, 256, 0, stream>>>(pred, gt, ws, out);
}

// Round 5
// 293.335 us; speedup vs baseline: 1.0460x; 1.0460x over previous
//
#include <hip/hip_runtime.h>
#include <math.h>

#define BB 32
#define NCLS 15
#define HH 256
#define WW 256
#define KK 500
#define HW (HH*WW)                 // 65536
#define NELEM (BB*NCLS*HW)         // 31457280
#define N4 (NELEM/4)               // 7864320 float4s
#define NM (BB*NCLS*16*16)         // 122880 multiplier slots
#define BK (BB*KK)                 // 16000

// k_main: 1536 blocks x 256 thr. Per outer iter each thread issues 8
// independent non-temporal dwordx4 loads (4 pred + 4 gt) spaced by the
// grid span SPAN, then computes. 5 * 4 * SPAN == N4 exactly.
// R4 lesson: wave-count concurrency doesn't move the ~2.47 TB/s read wall
// (480 vs 2048 blocks identical); this attacks per-wave MLP (VGPR=28 ->
// ~2 loads in flight) and cache-allocation overhead (nt) instead.
#define MG 1536
#define MT 256
#define SPAN (MG*MT)               // 393216
#define MITER 5

typedef float v4f __attribute__((ext_vector_type(4)));

// ws layout (floats):
//  f[0] = S  f[1] = num_pos  i[2] = last (init -1)  i[3] = corr block counter
//  f[4 .. 4+BK) = l_bk   f[16384 .. 16384+NM) = multiplier table M (init 1.0)
#define OFF_LBK 4
#define OFF_M   16384

__constant__ float c_gammas[15] = {2.7f,2.1f,2.4f,2.0f,3.0f,2.9f,3.0f,2.5f,
                                   2.1f,2.6f,2.0f,2.1f,2.7f,2.4f,2.2f};

// Raw HW transcendentals (glibc collides with __exp2f/__log2f names):
#define EXP2F(x) __builtin_amdgcn_exp2f(x)
#define LOG2F(x) __builtin_amdgcn_logf(x)
#define LN2 0.69314718055994530942f

__device__ __forceinline__ float elem(float p, float g, float gam, float& np) {
    float t    = 1.0f - g;
    float t2   = t * t;
    float negw = (g < 1.0f) ? t2 * t2 : 0.0f;          // (1-g)^4 * neg_ind
    float pw   = EXP2F(gam * LOG2F(p));                // p^gam (0 -> 0)
    float v    = (LN2 * LOG2F(1.0f - p + 1e-12f)) * pw * negw;
    if (g == 1.0f) {                                   // ~never taken
        np += 1.0f;
        v += (LN2 * LOG2F(p + 1e-12f)) * EXP2F(gam * LOG2F(1.0f - p));
    }
    return v;
}

__device__ __forceinline__ float quad(v4f p, v4f g, int i, float& np) {
    int c = ((unsigned)i >> 14) % (unsigned)NCLS;
    float gam = c_gammas[c];
    return gam * (elem(p.x, g.x, gam, np) + elem(p.y, g.y, gam, np)
                + elem(p.z, g.z, gam, np) + elem(p.w, g.w, gam, np));
}

__device__ __forceinline__ float blockReduceSum(float v) {
    __shared__ float sh[4];
    #pragma unroll
    for (int o = 32; o > 0; o >>= 1) v += __shfl_down(v, o);
    int lane = threadIdx.x & 63, w = threadIdx.x >> 6;
    if (lane == 0) sh[w] = v;
    __syncthreads();
    float r = 0.0f;
    if (threadIdx.x == 0) r = sh[0] + sh[1] + sh[2] + sh[3];
    __syncthreads();
    return r;   // valid on thread 0 only
}

// ---- init: zero scalars, last=-1, corr counter=0, M=1.0 ----
__global__ __launch_bounds__(256) void k_init(float* ws) {
    int i = blockIdx.x * blockDim.x + threadIdx.x;
    if (i == 0) {
        ws[0] = 0.0f;
        ws[1] = 0.0f;
        ((int*)ws)[2] = -1;
        ((int*)ws)[3] = 0;
    }
    if (i < NM) ws[OFF_M + i] = 1.0f;
}

// ---- per-(b,k): huber mean, l_bk, last, scatter-multiply into M ----
__global__ __launch_bounds__(256) void k_bk(const float* __restrict__ output,
                                            const int*   __restrict__ mask,
                                            const int*   __restrict__ ind,
                                            const float* __restrict__ target,
                                            const int*   __restrict__ inde,
                                            float* ws) {
    int t = blockIdx.x * blockDim.x + threadIdx.x;
    int lastv = -1;
    if (t < BK) {
        int b = t / KK;
        int pos = ind[t];                                    // 0..HW-1
        const float* ob = output + (size_t)b * 2 * HW;
        float p0 = ob[pos];
        float p1 = ob[HW + pos];
        float d0 = p0 - target[t*2 + 0];
        float d1 = p1 - target[t*2 + 1];
        float a0 = fabsf(d0), a1 = fabsf(d1);
        float h0 = (a0 < 1.0f) ? 0.5f*d0*d0 : a0 - 0.5f;
        float h1 = (a1 < 1.0f) ? 0.5f*d1*d1 : a1 - 0.5f;
        float l  = 0.5f * (h0 + h1);
        ws[OFF_LBK + t] = l;
        if (mask[t] != 0) {
            lastv = t;
            float factor = atanf(l) * 0.63661977236758134308f;  // 2/pi
            int ch = inde[t*3 + 0];
            int yy = inde[t*3 + 1];
            int xx = inde[t*3 + 2];
            int mi = ((b*NCLS + ch)*16 + yy)*16 + xx;
            unsigned int* addr = (unsigned int*)(ws + OFF_M + mi);
            unsigned int old = *addr, assumed;
            do {
                assumed = old;
                float nv = __uint_as_float(assumed) * factor;
                old = atomicCAS(addr, assumed, __float_as_uint(nv));
            } while (old != assumed);
        }
    }
    // block-level max of lastv -> one atomicMax per block
    __shared__ int shm[4];
    int v = lastv;
    #pragma unroll
    for (int o = 32; o > 0; o >>= 1) v = max(v, __shfl_down(v, o));
    int lane = threadIdx.x & 63, w = threadIdx.x >> 6;
    if (lane == 0) shm[w] = v;
    __syncthreads();
    if (threadIdx.x == 0) {
        int m = max(max(shm[0], shm[1]), max(shm[2], shm[3]));
        if (m >= 0) atomicMax(((int*)ws) + 2, m);
    }
}

// ---- main reduction: deep-MLP non-temporal streaming sweep ----
__global__ __launch_bounds__(256) void k_main(const v4f* __restrict__ pred,
                                              const v4f* __restrict__ gt,
                                              float* ws) {
    int t = blockIdx.x * MT + threadIdx.x;
    float acc = 0.0f, np = 0.0f;
    #pragma unroll 1
    for (int k = 0; k < MITER; ++k) {
        int i0 = t + k * 4 * SPAN;
        // 8 independent nt loads issued back-to-back (MLP depth 8/wave)
        v4f p0 = __builtin_nontemporal_load(pred + i0);
        v4f p1 = __builtin_nontemporal_load(pred + i0 + SPAN);
        v4f p2 = __builtin_nontemporal_load(pred + i0 + 2*SPAN);
        v4f p3 = __builtin_nontemporal_load(pred + i0 + 3*SPAN);
        v4f g0 = __builtin_nontemporal_load(gt + i0);
        v4f g1 = __builtin_nontemporal_load(gt + i0 + SPAN);
        v4f g2 = __builtin_nontemporal_load(gt + i0 + 2*SPAN);
        v4f g3 = __builtin_nontemporal_load(gt + i0 + 3*SPAN);
        acc += quad(p0, g0, i0,          np);
        acc += quad(p1, g1, i0 + SPAN,   np);
        acc += quad(p2, g2, i0 + 2*SPAN, np);
        acc += quad(p3, g3, i0 + 3*SPAN, np);
    }
    float bs = blockReduceSum(acc);
    if (threadIdx.x == 0 && bs != 0.0f) atomicAdd(&ws[0], bs);
    float bn = blockReduceSum(np);
    if (threadIdx.x == 0 && bn != 0.0f) atomicAdd(&ws[1], bn);
}

// ---- correction at scatter-modified locations + fused finalize ----
// grid must be exactly NM/256 = 480 blocks (counter pattern assumes it).
__global__ __launch_bounds__(256) void k_corr(const float* __restrict__ pred,
                                              const float* __restrict__ gt,
                                              float* ws, float* out) {
    int i = blockIdx.x * blockDim.x + threadIdx.x;
    float acc = 0.0f, dummy = 0.0f;
    float m = ws[OFF_M + i];
    if (m != 1.0f) {
        int x  = i & 15;
        int y  = (i >> 4) & 15;
        int bc = i >> 8;
        int c  = bc % NCLS;
        size_t off = ((size_t)bc << 16) + (size_t)(y * WW + x);
        float p = pred[off];
        float g = gt[off];
        float gam = c_gammas[c];
        acc = gam * (elem(p * m, g, gam, dummy) - elem(p, g, gam, dummy));
    }
    float bs = blockReduceSum(acc);
    if (threadIdx.x == 0) {
        if (bs != 0.0f) atomicAdd(&ws[0], bs);
        __threadfence();                                   // flush my add
        int done = atomicAdd(((int*)ws) + 3, 1);
        if (done == gridDim.x - 1) {                       // last block finalizes
            float S  = atomicAdd(&ws[0], 0.0f);            // coherent reads
            float np = atomicAdd(&ws[1], 0.0f);
            int last = ((volatile int*)ws)[2];             // written by k_bk (prior kernel)
            float loss0 = (last >= 0) ? ws[OFF_LBK + last] : 0.0f;
            float loss = loss0 - 0.5f * S;
            out[0] = (np == 0.0f) ? loss : loss / np;
        }
    }
}

extern "C" void kernel_launch(void* const* d_in, const int* in_sizes, int n_in,
                              void* d_out, int out_size, void* d_ws, size_t ws_size,
                              hipStream_t stream) {
    const float* pred   = (const float*)d_in[0];
    const float* gt     = (const float*)d_in[1];
    const float* output = (const float*)d_in[2];
    const int*   mask   = (const int*)d_in[3];
    const int*   ind    = (const int*)d_in[4];
    const float* target = (const float*)d_in[5];
    const int*   inde   = (const int*)d_in[6];
    float* ws  = (float*)d_ws;
    float* out = (float*)d_out;

    k_init<<<(NM + 255)/256, 256, 0, stream>>>(ws);
    k_bk  <<<(BK + 255)/256, 256, 0, stream>>>(output, mask, ind, target, inde, ws);
    k_main<<<MG, MT, 0, stream>>>((const v4f*)pred, (const v4f*)gt, ws);
    k_corr<<<NM/256, 256, 0, stream>>>(pred, gt, ws, out);
}